// Round 1
// baseline (487.032 us; speedup 1.0000x reference)
//
#include <hip/hip_runtime.h>
#include <hip/hip_bf16.h>

// ---------------------------------------------------------------------------
// Swin WindowAttention, fully fused per-window kernel (bf16 MFMA, fp32 accum)
//   x:(4096,49,256) f32 -> out:(4096,49,256) f32
//   per block: one window, 512 thr = 8 waves, wave h owns head h.
//   LDS 128 KiB: [xs 32K (later attn-out) | per-head: qk 8K (later P) + vt 4K]
//   All LDS rows XOR-swizzled: byte ^= (row&7)<<4  (bank-conflict fix, G4)
// ---------------------------------------------------------------------------

#define NTOK 49
#define CDIM 256
static constexpr float SCALE_Q = 0.17677669529663687f; // 32^-0.5

using bf16   = __bf16;
using bf16x8 = __attribute__((ext_vector_type(8))) __bf16;
using bf16x4 = __attribute__((ext_vector_type(4))) __bf16;
using f32x4  = __attribute__((ext_vector_type(4))) float;

#define WT_QKV_OFF 0
#define WT_PROJ_OFF (768 * 256 * 2)
#define CB_OFF (WT_PROJ_OFF + 256 * 256 * 2)
#define WS_NEEDED (CB_OFF + (size_t)64 * 8 * 49 * 49 * 4)

__global__ void prep_wqkv(const float* __restrict__ qkv_w, bf16* __restrict__ wt) {
    int idx = blockIdx.x * 256 + threadIdx.x;            // 768*256
    if (idx >= 768 * 256) return;
    int n = idx >> 8, k = idx & 255;
    float v = qkv_w[k * 768 + n];
    if (n < 256) v *= SCALE_Q;                           // fold q-scale
    wt[idx] = (bf16)v;                                   // wt[n][k]
}
__global__ void prep_wproj(const float* __restrict__ proj_w, bf16* __restrict__ wt) {
    int idx = blockIdx.x * 256 + threadIdx.x;            // 256*256
    if (idx >= 256 * 256) return;
    int n = idx >> 8, k = idx & 255;
    wt[idx] = (bf16)proj_w[k * 256 + n];                 // wt[n][k]
}
__global__ void prep_cb(const float* __restrict__ bias_table, const int* __restrict__ rel_index,
                        const float* __restrict__ mask, float* __restrict__ cb) {
    int idx = blockIdx.x * 256 + threadIdx.x;            // 64*8*49*49
    if (idx >= 64 * 8 * 49 * 49) return;
    int j = idx % 49;
    int t = idx / 49;
    int i = t % 49; t /= 49;
    int h = t % 8;
    int w = t / 8;
    cb[idx] = bias_table[rel_index[i * 49 + j] * 8 + h] + mask[(w * 49 + i) * 49 + j];
}

__global__ __launch_bounds__(512, 2) void fused_attn(
    const float* __restrict__ x,
    const float* __restrict__ qkv_b,
    const float* __restrict__ proj_b,
    const bf16* __restrict__ wt_qkv,
    const bf16* __restrict__ wt_proj,
    const float* __restrict__ cb,
    float* __restrict__ out)
{
    extern __shared__ char smem[];
    const int b    = blockIdx.x;
    const int tid  = threadIdx.x;
    const int lane = tid & 63;
    const int h    = tid >> 6;     // wave id == head
    const int l15  = lane & 15;
    const int g    = lane >> 4;

    char* xs = smem;                           // 32 KB
    char* qk = smem + 32768 + h * 12288;       // 8 KB/head
    char* vt = qk + 8192;                      // 4 KB/head

    // ---- stage x -> xs (bf16, rows 49..63 zeroed, swizzled) ----
    {
        const float* xb = x + (size_t)b * (NTOK * CDIM);
        #pragma unroll
        for (int it = 0; it < 8; ++it) {
            int idx = it * 512 + tid;          // 64 rows x 64 float4-chunks
            int row = idx >> 6, c4 = idx & 63;
            float4 v = make_float4(0.f, 0.f, 0.f, 0.f);
            if (row < NTOK) v = ((const float4*)xb)[row * 64 + c4];
            bf16x4 o;
            o[0] = (bf16)v.x; o[1] = (bf16)v.y; o[2] = (bf16)v.z; o[3] = (bf16)v.w;
            *(bf16x4*)(xs + row * 512 + ((c4 * 8) ^ ((row & 7) << 4))) = o;
        }
    }
    __syncthreads();

    // ---- QKV GEMM: [64x256] @ [256x96] per wave ----
    {
        f32x4 acc[6][4];
        #pragma unroll
        for (int ni = 0; ni < 6; ++ni)
            #pragma unroll
            for (int mi = 0; mi < 4; ++mi)
                acc[ni][mi] = (f32x4){0.f, 0.f, 0.f, 0.f};

        const int nb[3] = { h * 32, 256 + h * 32, 512 + h * 32 };
        #pragma unroll
        for (int kk = 0; kk < 8; ++kk) {
            bf16x8 a[4];
            #pragma unroll
            for (int mi = 0; mi < 4; ++mi) {
                int row = mi * 16 + l15;
                a[mi] = *(const bf16x8*)(xs + row * 512 + ((kk * 64 + g * 16) ^ ((row & 7) << 4)));
            }
            #pragma unroll
            for (int ni = 0; ni < 6; ++ni) {
                int ncol = nb[ni >> 1] + (ni & 1) * 16 + l15;
                bf16x8 bfr = *(const bf16x8*)(wt_qkv + ncol * 256 + kk * 32 + g * 8);
                #pragma unroll
                for (int mi = 0; mi < 4; ++mi)
                    acc[ni][mi] = __builtin_amdgcn_mfma_f32_16x16x32_bf16(a[mi], bfr, acc[ni][mi], 0, 0, 0);
            }
        }
        __syncthreads();   // all waves done reading xs

        #pragma unroll
        for (int ni = 0; ni < 6; ++ni) {
            int col = nb[ni >> 1] + (ni & 1) * 16 + l15;
            float bias = qkv_b[col];
            if (col < 256) bias *= SCALE_Q;
            #pragma unroll
            for (int mi = 0; mi < 4; ++mi) {
                #pragma unroll
                for (int r = 0; r < 4; ++r) {
                    int qrow = mi * 16 + g * 4 + r;
                    bf16 bv = (bf16)(acc[ni][mi][r] + bias);
                    int d = (ni & 1) * 16 + l15;
                    if (ni < 2) {
                        *(bf16*)(qk + qrow * 128 + ((d * 2) ^ ((qrow & 7) << 4))) = bv;
                    } else if (ni < 4) {
                        *(bf16*)(qk + qrow * 128 + ((64 + d * 2) ^ ((qrow & 7) << 4))) = bv;
                    } else {
                        *(bf16*)(vt + d * 128 + ((qrow * 2) ^ ((d & 7) << 4))) = bv;
                    }
                }
            }
        }
    }

    // ---- scores (64x64, K=32) ----
    f32x4 s[4][4];
    {
        #pragma unroll
        for (int mi = 0; mi < 4; ++mi)
            #pragma unroll
            for (int ni = 0; ni < 4; ++ni)
                s[mi][ni] = (f32x4){0.f, 0.f, 0.f, 0.f};

        bf16x8 aq[4];
        #pragma unroll
        for (int mi = 0; mi < 4; ++mi) {
            int row = mi * 16 + l15;
            aq[mi] = *(const bf16x8*)(qk + row * 128 + ((g * 16) ^ ((row & 7) << 4)));
        }
        #pragma unroll
        for (int ni = 0; ni < 4; ++ni) {
            int key = ni * 16 + l15;
            bf16x8 bk = *(const bf16x8*)(qk + key * 128 + ((64 + g * 16) ^ ((key & 7) << 4)));
            #pragma unroll
            for (int mi = 0; mi < 4; ++mi)
                s[mi][ni] = __builtin_amdgcn_mfma_f32_16x16x32_bf16(aq[mi], bk, s[mi][ni], 0, 0, 0);
        }
    }

    // ---- +bias+mask, softmax, P (normalized, in s) ----
    {
        const float* cbh = cb + ((size_t)((b & 63) * 8 + h)) * (49 * 49);
        #pragma unroll
        for (int ni = 0; ni < 4; ++ni) {
            int j = ni * 16 + l15;
            #pragma unroll
            for (int mi = 0; mi < 4; ++mi) {
                #pragma unroll
                for (int r = 0; r < 4; ++r) {
                    int i = mi * 16 + g * 4 + r;
                    float v = s[mi][ni][r];
                    if (j < 49) {
                        if (i < 49) v += cbh[i * 49 + j];
                    } else {
                        v = -1e30f;
                    }
                    s[mi][ni][r] = v;
                }
            }
        }
        #pragma unroll
        for (int mi = 0; mi < 4; ++mi) {
            #pragma unroll
            for (int r = 0; r < 4; ++r) {
                float m = fmaxf(fmaxf(s[mi][0][r], s[mi][1][r]), fmaxf(s[mi][2][r], s[mi][3][r]));
                m = fmaxf(m, __shfl_xor(m, 1));
                m = fmaxf(m, __shfl_xor(m, 2));
                m = fmaxf(m, __shfl_xor(m, 4));
                m = fmaxf(m, __shfl_xor(m, 8));
                float e0 = __expf(s[mi][0][r] - m);
                float e1 = __expf(s[mi][1][r] - m);
                float e2 = __expf(s[mi][2][r] - m);
                float e3 = __expf(s[mi][3][r] - m);
                float sum = e0 + e1 + e2 + e3;
                sum += __shfl_xor(sum, 1);
                sum += __shfl_xor(sum, 2);
                sum += __shfl_xor(sum, 4);
                sum += __shfl_xor(sum, 8);
                float rs = 1.f / sum;
                s[mi][0][r] = e0 * rs;
                s[mi][1][r] = e1 * rs;
                s[mi][2][r] = e2 * rs;
                s[mi][3][r] = e3 * rs;
            }
        }
        // write P over qk region (same-wave reuse; q,k dead)
        #pragma unroll
        for (int mi = 0; mi < 4; ++mi) {
            #pragma unroll
            for (int r = 0; r < 4; ++r) {
                int qrow = mi * 16 + g * 4 + r;
                #pragma unroll
                for (int ni = 0; ni < 4; ++ni) {
                    int key = ni * 16 + l15;
                    *(bf16*)(qk + qrow * 128 + ((key * 2) ^ ((qrow & 7) << 4))) = (bf16)s[mi][ni][r];
                }
            }
        }
    }

    // ---- PV: out^T = V^T (32x64) . P^T (64x64) ----
    {
        f32x4 o[2][4];
        #pragma unroll
        for (int mi = 0; mi < 2; ++mi)
            #pragma unroll
            for (int ni = 0; ni < 4; ++ni)
                o[mi][ni] = (f32x4){0.f, 0.f, 0.f, 0.f};

        #pragma unroll
        for (int kk = 0; kk < 2; ++kk) {
            bf16x8 av[2];
            #pragma unroll
            for (int mi = 0; mi < 2; ++mi) {
                int d = mi * 16 + l15;
                av[mi] = *(const bf16x8*)(vt + d * 128 + ((kk * 64 + g * 16) ^ ((d & 7) << 4)));
            }
            #pragma unroll
            for (int ni = 0; ni < 4; ++ni) {
                int q = ni * 16 + l15;
                bf16x8 bp = *(const bf16x8*)(qk + q * 128 + ((kk * 64 + g * 16) ^ ((q & 7) << 4)));
                #pragma unroll
                for (int mi = 0; mi < 2; ++mi)
                    o[mi][ni] = __builtin_amdgcn_mfma_f32_16x16x32_bf16(av[mi], bp, o[mi][ni], 0, 0, 0);
            }
        }
        #pragma unroll
        for (int mi = 0; mi < 2; ++mi) {
            #pragma unroll
            for (int ni = 0; ni < 4; ++ni) {
                #pragma unroll
                for (int r = 0; r < 4; ++r) {
                    int d = mi * 16 + g * 4 + r;
                    int q = ni * 16 + l15;
                    int cbyte = (h * 32 + d) * 2;
                    *(bf16*)(xs + q * 512 + (cbyte ^ ((q & 7) << 4))) = (bf16)o[mi][ni][r];
                }
            }
        }
    }
    __syncthreads();

    // ---- proj: [64x256] @ [256x32] per wave + bias -> out ----
    {
        f32x4 po[2][4];
        #pragma unroll
        for (int ni = 0; ni < 2; ++ni)
            #pragma unroll
            for (int mi = 0; mi < 4; ++mi)
                po[ni][mi] = (f32x4){0.f, 0.f, 0.f, 0.f};

        #pragma unroll
        for (int kk = 0; kk < 8; ++kk) {
            bf16x8 a[4];
            #pragma unroll
            for (int mi = 0; mi < 4; ++mi) {
                int row = mi * 16 + l15;
                a[mi] = *(const bf16x8*)(xs + row * 512 + ((kk * 64 + g * 16) ^ ((row & 7) << 4)));
            }
            #pragma unroll
            for (int ni = 0; ni < 2; ++ni) {
                int col = h * 32 + ni * 16 + l15;
                bf16x8 bw = *(const bf16x8*)(wt_proj + col * 256 + kk * 32 + g * 8);
                #pragma unroll
                for (int mi = 0; mi < 4; ++mi)
                    po[ni][mi] = __builtin_amdgcn_mfma_f32_16x16x32_bf16(a[mi], bw, po[ni][mi], 0, 0, 0);
            }
        }
        float* outb = out + (size_t)b * (NTOK * CDIM);
        #pragma unroll
        for (int ni = 0; ni < 2; ++ni) {
            int col = h * 32 + ni * 16 + l15;
            float pb = proj_b[col];
            #pragma unroll
            for (int mi = 0; mi < 4; ++mi) {
                #pragma unroll
                for (int r = 0; r < 4; ++r) {
                    int row = mi * 16 + g * 4 + r;
                    if (row < NTOK) outb[row * 256 + col] = po[ni][mi][r] + pb;
                }
            }
        }
    }
}

extern "C" void kernel_launch(void* const* d_in, const int* in_sizes, int n_in,
                              void* d_out, int out_size, void* d_ws, size_t ws_size,
                              hipStream_t stream) {
    const float* x          = (const float*)d_in[0];
    const float* mask       = (const float*)d_in[1];
    const float* qkv_w      = (const float*)d_in[2];
    const float* qkv_b      = (const float*)d_in[3];
    const float* proj_w     = (const float*)d_in[4];
    const float* proj_b     = (const float*)d_in[5];
    const float* bias_table = (const float*)d_in[6];
    const int*   rel_index  = (const int*)d_in[7];
    float* out = (float*)d_out;

    if (ws_size < WS_NEEDED) return;  // needs ~5.5 MB scratch

    char* ws = (char*)d_ws;
    bf16*  wt_qkv  = (bf16*)(ws + WT_QKV_OFF);
    bf16*  wt_proj = (bf16*)(ws + WT_PROJ_OFF);
    float* cb      = (float*)(ws + CB_OFF);

    prep_wqkv <<<768, 256, 0, stream>>>(qkv_w, wt_qkv);
    prep_wproj<<<256, 256, 0, stream>>>(proj_w, wt_proj);
    prep_cb   <<<(64 * 8 * 49 * 49 + 255) / 256, 256, 0, stream>>>(bias_table, rel_index, mask, cb);

    hipFuncSetAttribute((const void*)fused_attn, hipFuncAttributeMaxDynamicSharedMemorySize, 131072);
    fused_attn<<<4096, 512, 131072, stream>>>(x, qkv_b, proj_b, wt_qkv, wt_proj, cb, out);
}